// Round 1
// baseline (2572.604 us; speedup 1.0000x reference)
//
#include <hip/hip_runtime.h>

#define NN 500000
#define FF 128
#define HH 256
#define CC 40
#define CHK 64   // H-chunk width

// ---------------- index kernels ----------------

__global__ void k_init_fp(int* fp) {
    int i = blockIdx.x * 256 + threadIdx.x;
    if (i < NN) fp[i] = 0x7FFFFFFF;
}

__global__ void k_amin(const int* __restrict__ ei, int* fp) {
    int i = blockIdx.x * 256 + threadIdx.x;
    if (i < NN) atomicMin(&fp[ei[2 * i]], i);
}

__global__ void k_count(const int* __restrict__ ei, const int* __restrict__ fp,
                        int* __restrict__ bsums) {
    int i = blockIdx.x * 256 + threadIdx.x;
    int f = 0;
    if (i < NN) f = (fp[ei[2 * i]] == i) ? 1 : 0;
    __shared__ int sh[256];
    sh[threadIdx.x] = f;
    __syncthreads();
    for (int s = 128; s > 0; s >>= 1) {
        if (threadIdx.x < s) sh[threadIdx.x] += sh[threadIdx.x + s];
        __syncthreads();
    }
    if (threadIdx.x == 0) bsums[blockIdx.x] = sh[0];
}

__global__ void k_scan(const int* __restrict__ bsums, int* __restrict__ bofs, int nb) {
    __shared__ int sh[256];
    int carry = 0;
    for (int base = 0; base < nb; base += 256) {
        int i = base + threadIdx.x;
        int v = (i < nb) ? bsums[i] : 0;
        sh[threadIdx.x] = v;
        __syncthreads();
        for (int s = 1; s < 256; s <<= 1) {
            int t = (threadIdx.x >= s) ? sh[threadIdx.x - s] : 0;
            __syncthreads();
            sh[threadIdx.x] += t;
            __syncthreads();
        }
        if (i < nb) bofs[i] = carry + sh[threadIdx.x] - v;   // exclusive
        carry += sh[255];
        __syncthreads();
    }
}

__global__ void k_rank(const int* __restrict__ ei, const int* __restrict__ fp,
                       const int* __restrict__ bofs, int* __restrict__ rank) {
    int i = blockIdx.x * 256 + threadIdx.x;
    int s = 0, f = 0;
    if (i < NN) { s = ei[2 * i]; f = (fp[s] == i) ? 1 : 0; }
    __shared__ int sh[256];
    sh[threadIdx.x] = f;
    __syncthreads();
    for (int st = 1; st < 256; st <<= 1) {
        int t = (threadIdx.x >= st) ? sh[threadIdx.x - st] : 0;
        __syncthreads();
        sh[threadIdx.x] += t;
        __syncthreads();
    }
    if (f) rank[s] = bofs[blockIdx.x] + sh[threadIdx.x] - 1;  // exclusive prefix
}

// ---------------- GEMM1 (x@W1 chunk + bias + relu) fused with segment scatter ----------------
// tile: 64 rows x 64 cols (one H-chunk), K = 128 (full)

__global__ __launch_bounds__(256) void k_gemm1(
    const float* __restrict__ x, const float* __restrict__ W1,
    const float* __restrict__ b1, const int* __restrict__ ei,
    const int* __restrict__ rank, float* __restrict__ aggc, int chunk)
{
    __shared__ float Xs[128][68];   // [k][row], padded
    __shared__ float Ws[128][64];   // [k][col]
    __shared__ int   mseg[64];
    const int tid = threadIdx.x;
    const long long row0 = (long long)blockIdx.x * 64;

    if (tid < 64) {
        long long i = row0 + tid;
        int m = 0;
        if (i < NN) {
            int s1 = ei[2 * i];
            int s2 = ei[2 * (long long)s1];
            m = rank[s2];
        }
        mseg[tid] = m;
    }

    // X tile: rows row0..row0+63 are contiguous (64*128 floats); transpose into LDS
    {
        const float* src = x + row0 * FF;
        const long long maxe = ((long long)NN - row0) * FF;
#pragma unroll
        for (int it = 0; it < 8; ++it) {
            long long e = (long long)tid * 4 + (long long)it * 1024;
            long long ee = (e < maxe) ? e : 0;
            float4 v = *(const float4*)(src + ee);
            int r = (int)(e >> 7), k = (int)(e & 127);
            Xs[k][r] = v.x; Xs[k + 1][r] = v.y; Xs[k + 2][r] = v.z; Xs[k + 3][r] = v.w;
        }
    }
    // W1 chunk: [128][64]
    {
        const float* srcw = W1 + chunk * CHK;
#pragma unroll
        for (int it = 0; it < 8; ++it) {
            int e = tid * 4 + it * 1024;
            int k = e >> 6, j = e & 63;
            float4 v = *(const float4*)(srcw + (long long)k * HH + j);
            *(float4*)&Ws[k][j] = v;
        }
    }
    __syncthreads();

    const int tx = tid & 15, ty = tid >> 4;   // tx: 16 col-groups, ty: 16 row-groups
    float acc[4][4] = {};
#pragma unroll 4
    for (int k = 0; k < 128; ++k) {
        float4 av = *(const float4*)&Xs[k][ty * 4];
        float4 bv = *(const float4*)&Ws[k][tx * 4];
        float a[4] = {av.x, av.y, av.z, av.w};
        float b[4] = {bv.x, bv.y, bv.z, bv.w};
#pragma unroll
        for (int i2 = 0; i2 < 4; ++i2)
#pragma unroll
            for (int j2 = 0; j2 < 4; ++j2)
                acc[i2][j2] += a[i2] * b[j2];
    }

    float bb[4];
#pragma unroll
    for (int j2 = 0; j2 < 4; ++j2) bb[j2] = b1[chunk * CHK + tx * 4 + j2];

#pragma unroll
    for (int i2 = 0; i2 < 4; ++i2) {
        long long row = row0 + ty * 4 + i2;
        if (row < NN) {
            float* dst = aggc + (long long)mseg[ty * 4 + i2] * CHK + tx * 4;
#pragma unroll
            for (int j2 = 0; j2 < 4; ++j2) {
                float v = acc[i2][j2] + bb[j2];
                atomicAdd(dst + j2, v > 0.f ? v : 0.f);   // relu BEFORE aggregation
            }
        }
    }
}

// ---------------- GEMM2: out (+)= relu(aggc) @ W2[chunk] (+ b2 on chunk 0) ----------------
// tile: 128 rows x 40 cols, K = 64; block = 128 threads, 4 rows x 10 cols per thread

__global__ __launch_bounds__(128) void k_gemm2(
    const float* __restrict__ aggc, const float* __restrict__ W2,
    const float* __restrict__ b2, float* __restrict__ out, int chunk)
{
    __shared__ float As[128][69];       // [row][k], pad 69 -> conflict-free-ish
    __shared__ float Ws2[CHK * CC];     // [k][c] linear, 2560 floats
    const int tid = threadIdx.x;
    const long long row0 = (long long)blockIdx.x * 128;

    // A tile (relu applied on load): 128x64 floats, contiguous in aggc
    {
        const float* src = aggc + row0 * CHK;
        const long long maxe = ((long long)NN - row0) * CHK;
#pragma unroll
        for (int it = 0; it < 16; ++it) {
            long long e = (long long)tid * 4 + (long long)it * 512;
            long long ee = (e < maxe) ? e : 0;
            float4 v = *(const float4*)(src + ee);
            int r = (int)(e >> 6), k = (int)(e & 63);
            As[r][k]     = v.x > 0.f ? v.x : 0.f;
            As[r][k + 1] = v.y > 0.f ? v.y : 0.f;
            As[r][k + 2] = v.z > 0.f ? v.z : 0.f;
            As[r][k + 3] = v.w > 0.f ? v.w : 0.f;
        }
    }
    {
        const float* srcw = W2 + chunk * CHK * CC;
#pragma unroll
        for (int it = 0; it < 20; ++it) {
            int e = tid + it * 128;
            Ws2[e] = srcw[e];
        }
    }
    __syncthreads();

    const int cg = tid & 3;    // col group: cols cg*10 .. cg*10+9
    const int rg = tid >> 2;   // row group: rows rg*4 .. rg*4+3
    float acc[4][10] = {};
    for (int k = 0; k < CHK; ++k) {
        float a[4];
#pragma unroll
        for (int j = 0; j < 4; ++j) a[j] = As[rg * 4 + j][k];
        float b[10];
#pragma unroll
        for (int j = 0; j < 5; ++j) {
            float2 w = *(const float2*)&Ws2[k * CC + cg * 10 + j * 2];
            b[j * 2] = w.x; b[j * 2 + 1] = w.y;
        }
#pragma unroll
        for (int i2 = 0; i2 < 4; ++i2)
#pragma unroll
            for (int j2 = 0; j2 < 10; ++j2)
                acc[i2][j2] += a[i2] * b[j2];
    }

#pragma unroll
    for (int i2 = 0; i2 < 4; ++i2) {
        long long row = row0 + rg * 4 + i2;
        if (row < NN) {
            float* po = out + row * CC + cg * 10;
            if (chunk == 0) {
#pragma unroll
                for (int j2 = 0; j2 < 10; ++j2) po[j2] = acc[i2][j2] + b2[cg * 10 + j2];
            } else {
#pragma unroll
                for (int j2 = 0; j2 < 10; ++j2) po[j2] += acc[i2][j2];
            }
        }
    }
}

// ---------------- launch ----------------

extern "C" void kernel_launch(void* const* d_in, const int* in_sizes, int n_in,
                              void* d_out, int out_size, void* d_ws, size_t ws_size,
                              hipStream_t stream) {
    const float* x  = (const float*)d_in[0];
    const int*   ei = (const int*)d_in[1];
    const float* W1 = (const float*)d_in[2];
    const float* b1 = (const float*)d_in[3];
    const float* W2 = (const float*)d_in[4];
    const float* b2 = (const float*)d_in[5];
    float* out = (float*)d_out;

    char* ws = (char*)d_ws;
    int* fp     = (int*)(ws);                       // N ints
    int* rank   = (int*)(ws + 4ll * NN);            // N ints
    int* bsums  = (int*)(ws + 8ll * NN);            // 2048 ints
    int* bofs   = (int*)(ws + 8ll * NN + 8192);     // 2048 ints
    float* aggc = (float*)(ws + 8ll * NN + 16384);  // N*64 floats = 128 MB

    const int NB = (NN + 255) / 256;  // 1954

    hipLaunchKernelGGL(k_init_fp, dim3(NB), dim3(256), 0, stream, fp);
    hipLaunchKernelGGL(k_amin,    dim3(NB), dim3(256), 0, stream, ei, fp);
    hipLaunchKernelGGL(k_count,   dim3(NB), dim3(256), 0, stream, ei, fp, bsums);
    hipLaunchKernelGGL(k_scan,    dim3(1),  dim3(256), 0, stream, bsums, bofs, NB);
    hipLaunchKernelGGL(k_rank,    dim3(NB), dim3(256), 0, stream, ei, fp, bofs, rank);

    for (int c = 0; c < 4; ++c) {
        hipMemsetAsync(aggc, 0, (size_t)NN * CHK * sizeof(float), stream);
        hipLaunchKernelGGL(k_gemm1, dim3((NN + 63) / 64),   dim3(256), 0, stream,
                           x, W1, b1, ei, rank, aggc, c);
        hipLaunchKernelGGL(k_gemm2, dim3((NN + 127) / 128), dim3(128), 0, stream,
                           aggc, W2, b2, out, c);
    }
}

// Round 3
// 969.016 us; speedup vs baseline: 2.6549x; 2.6549x over previous
//
#include <hip/hip_runtime.h>

#define NN 500000
#define FF 128
#define HH 256
#define CC 40
#define NB256 ((NN + 255) / 256)   // 1954

typedef __attribute__((ext_vector_type(8))) short bf16x8;
typedef __attribute__((ext_vector_type(4))) float f32x4;

__device__ inline unsigned short f2b(float f) {
    unsigned u = __builtin_bit_cast(unsigned, f);
    return (unsigned short)((u + 0x7FFF + ((u >> 16) & 1)) >> 16);
}
__device__ inline unsigned f2b2(float lo, float hi) {
    unsigned ul = __builtin_bit_cast(unsigned, lo);
    unsigned uh = __builtin_bit_cast(unsigned, hi);
    unsigned rl = (ul + 0x7FFF + ((ul >> 16) & 1)) >> 16;
    unsigned rh = (uh + 0x7FFF + ((uh >> 16) & 1)) >> 16;
    return rl | (rh << 16);
}

// ---------------- index / CSR kernels ----------------

__global__ void k_init(int* fp, int* cnt, int* cur) {
    int i = blockIdx.x * 256 + threadIdx.x;
    if (i < NN) { fp[i] = 0x7FFFFFFF; cnt[i] = 0; cur[i] = 0; }
}

__global__ void k_amin(const int* __restrict__ ei, int* fp) {
    int i = blockIdx.x * 256 + threadIdx.x;
    if (i < NN) atomicMin(&fp[ei[2 * i]], i);
}

__global__ void k_count(const int* __restrict__ ei, const int* __restrict__ fp,
                        int* __restrict__ bsums) {
    int i = blockIdx.x * 256 + threadIdx.x;
    int f = 0;
    if (i < NN) f = (fp[ei[2 * i]] == i) ? 1 : 0;
    __shared__ int sh[256];
    sh[threadIdx.x] = f;
    __syncthreads();
    for (int s = 128; s > 0; s >>= 1) {
        if (threadIdx.x < s) sh[threadIdx.x] += sh[threadIdx.x + s];
        __syncthreads();
    }
    if (threadIdx.x == 0) bsums[blockIdx.x] = sh[0];
}

__global__ void k_scan(const int* __restrict__ bsums, int* __restrict__ bofs, int nb) {
    __shared__ int sh[256];
    int carry = 0;
    for (int base = 0; base < nb; base += 256) {
        int i = base + threadIdx.x;
        int v = (i < nb) ? bsums[i] : 0;
        sh[threadIdx.x] = v;
        __syncthreads();
        for (int s = 1; s < 256; s <<= 1) {
            int t = (threadIdx.x >= s) ? sh[threadIdx.x - s] : 0;
            __syncthreads();
            sh[threadIdx.x] += t;
            __syncthreads();
        }
        if (i < nb) bofs[i] = carry + sh[threadIdx.x] - v;   // exclusive
        carry += sh[255];
        __syncthreads();
    }
}

__global__ void k_rank(const int* __restrict__ ei, const int* __restrict__ fp,
                       const int* __restrict__ bofs, int* __restrict__ rank) {
    int i = blockIdx.x * 256 + threadIdx.x;
    int s = 0, f = 0;
    if (i < NN) { s = ei[2 * i]; f = (fp[s] == i) ? 1 : 0; }
    __shared__ int sh[256];
    sh[threadIdx.x] = f;
    __syncthreads();
    for (int st = 1; st < 256; st <<= 1) {
        int t = (threadIdx.x >= st) ? sh[threadIdx.x - st] : 0;
        __syncthreads();
        sh[threadIdx.x] += t;
        __syncthreads();
    }
    if (f) rank[s] = bofs[blockIdx.x] + sh[threadIdx.x] - 1;
}

__global__ void k_mapped(const int* __restrict__ ei, const int* __restrict__ rank,
                         int* __restrict__ mapped, int* __restrict__ cnt) {
    int i = blockIdx.x * 256 + threadIdx.x;
    if (i < NN) {
        int s1 = ei[2 * i];
        int s2 = ei[2 * (long long)s1];
        int m = rank[s2];
        mapped[i] = m;
        atomicAdd(&cnt[m], 1);
    }
}

__global__ void k_block_scan(const int* __restrict__ in, int* __restrict__ outp,
                             int* __restrict__ bsums, int n) {
    int i = blockIdx.x * 256 + threadIdx.x;
    int v = (i < n) ? in[i] : 0;
    __shared__ int sh[256];
    sh[threadIdx.x] = v;
    __syncthreads();
    for (int s = 1; s < 256; s <<= 1) {
        int t = (threadIdx.x >= s) ? sh[threadIdx.x - s] : 0;
        __syncthreads();
        sh[threadIdx.x] += t;
        __syncthreads();
    }
    if (i < n) outp[i] = sh[threadIdx.x] - v;     // exclusive within block
    if (threadIdx.x == 255) bsums[blockIdx.x] = sh[255];
}

__global__ void k_add_off(int* __restrict__ outp, const int* __restrict__ bofs, int n) {
    int i = blockIdx.x * 256 + threadIdx.x;
    if (i < n) outp[i] += bofs[blockIdx.x];
    if (i == 0) outp[n] = n;                      // rowptr[NN] = NN (total edges)
}

__global__ void k_scatter(const int* __restrict__ mapped, const int* __restrict__ rowptr,
                          int* __restrict__ cur, int* __restrict__ col) {
    int i = blockIdx.x * 256 + threadIdx.x;
    if (i < NN) {
        int m = mapped[i];
        int loc = rowptr[m] + atomicAdd(&cur[m], 1);
        col[loc] = i;
    }
}

__global__ void k_cvtW1(const float* __restrict__ W1, unsigned short* __restrict__ W1T) {
    int i = blockIdx.x * 256 + threadIdx.x;       // over HH*FF, layout W1T[n][k]
    if (i < HH * FF) {
        int n = i >> 7, k = i & 127;
        W1T[i] = f2b(W1[k * HH + n]);
    }
}

__global__ void k_cvtW2(const float* __restrict__ W2, unsigned short* __restrict__ W2T) {
    int i = blockIdx.x * 256 + threadIdx.x;       // over 48*HH, layout W2T[n][k], n>=CC zero
    if (i < 48 * HH) {
        int n = i >> 8, k = i & 255;
        W2T[i] = (n < CC) ? f2b(W2[k * CC + n]) : (unsigned short)0;
    }
}

// ---------------- stage B1: hperm[j] = relu(x[col[j]] @ W1[:,chunk] + b1) in bf16 ----------------
// block: 64 permuted rows x 64 h-cols, K=128, 4 waves, MFMA 16x16x32

__global__ __launch_bounds__(256) void k_h(
    const float* __restrict__ x, const unsigned short* __restrict__ W1T,
    const float* __restrict__ b1, const int* __restrict__ col,
    unsigned short* __restrict__ hperm, int chunk)
{
    __shared__ __align__(16) unsigned short Xs[64][136];  // [m][k] pad 8
    __shared__ __align__(16) unsigned short Ws[64][136];  // [n][k] pad 8
    const int tid = threadIdx.x;
    const long long j0 = (long long)blockIdx.x * 64;

    // stage W1T chunk rows (64 n-rows x 128 bf16 = 16 uint4/row, 4 threads/row -> 4 uint4 each)
    {
        int n = tid >> 2, c0 = tid & 3;
        const uint4* src = (const uint4*)(W1T + (chunk * 64 + n) * FF);
        uint4* drow = (uint4*)&Ws[n][0];
        drow[c0]      = src[c0];
        drow[c0 + 4]  = src[c0 + 4];
        drow[c0 + 8]  = src[c0 + 8];
        drow[c0 + 12] = src[c0 + 12];
    }
    // gather + convert x rows
    {
        int r = tid >> 2, q = tid & 3;
        long long j = j0 + r;
        int e = (j < NN) ? col[j] : 0;
        const float4* src = (const float4*)(x + (long long)e * FF + q * 32);
        unsigned* dst = (unsigned*)&Xs[r][q * 32];
#pragma unroll
        for (int it = 0; it < 8; ++it) {
            float4 v = src[it];
            dst[it * 2]     = f2b2(v.x, v.y);
            dst[it * 2 + 1] = f2b2(v.z, v.w);
        }
    }
    __syncthreads();

    const int lane = tid & 63, wave = tid >> 6;
    const int l16 = lane & 15, quad = lane >> 4;
    f32x4 acc[4] = {{0,0,0,0},{0,0,0,0},{0,0,0,0},{0,0,0,0}};
#pragma unroll
    for (int kk = 0; kk < 4; ++kk) {
        bf16x8 a = *(const bf16x8*)&Xs[wave * 16 + l16][kk * 32 + quad * 8];
#pragma unroll
        for (int nt = 0; nt < 4; ++nt) {
            bf16x8 b = *(const bf16x8*)&Ws[nt * 16 + l16][kk * 32 + quad * 8];
            acc[nt] = __builtin_amdgcn_mfma_f32_16x16x32_bf16(a, b, acc[nt], 0, 0, 0);
        }
    }
    __syncthreads();

    // epilogue: relu(acc + b1) -> bf16 tile in LDS (reuse Xs), then coalesced store
    unsigned short (*Hs)[72] = (unsigned short(*)[72])&Xs[0][0];
#pragma unroll
    for (int nt = 0; nt < 4; ++nt) {
        float bias = b1[chunk * 64 + nt * 16 + l16];
#pragma unroll
        for (int reg = 0; reg < 4; ++reg) {
            int row = wave * 16 + quad * 4 + reg;       // C/D: row=quad*4+reg, col=lane&15
            float v = acc[nt][reg] + bias;
            Hs[row][nt * 16 + l16] = f2b(v > 0.f ? v : 0.f);
        }
    }
    __syncthreads();
    {
        int r = tid >> 2, c4 = tid & 3;
        const uint4* srow = (const uint4*)&Hs[r][0];    // pitch 144B, 16B aligned
        uint4* drow = (uint4*)(hperm + (j0 + r) * 64);
        drow[c4] = srow[c4];
        drow[c4 + 4] = srow[c4 + 4];
    }
}

// ---------------- stage B2: out[m] (+)= relu(segsum(hperm)) @ W2[chunk] (+b2) ----------------
// block: 128 output rows; gather contiguous hperm runs; MFMA 16x16x32, K=64, ncols 48 (40 used)

__global__ __launch_bounds__(256) void k_out(
    const unsigned short* __restrict__ hperm, const unsigned short* __restrict__ W2T,
    const float* __restrict__ b2, const int* __restrict__ rowptr,
    float* __restrict__ out, int chunk)
{
    __shared__ __align__(16) unsigned short As[128][72];  // [m][k] pad 8
    __shared__ __align__(16) unsigned short Bs[48][72];   // [n][k] pad 8
    __shared__ int rp[129];
    const int tid = threadIdx.x;
    const long long m0 = (long long)blockIdx.x * 128;

    if (tid < 129) {
        long long mi = m0 + tid; if (mi > NN) mi = NN;
        rp[tid] = rowptr[mi];
    }
    for (int u = tid; u < 48 * 8; u += 256) {             // Bs: 48 rows x 128B
        int n = u >> 3, c = u & 7;
        ((uint4*)&Bs[n][0])[c] = ((const uint4*)(W2T + n * HH + chunk * 64))[c];
    }
    __syncthreads();

    // segment-sum gather: thread = (m-sub, 4-col group)
    const int cg = tid & 15;       // cols cg*4..cg*4+3
    const int ms = tid >> 4;       // 0..15
#pragma unroll
    for (int p = 0; p < 8; ++p) {
        int m = p * 16 + ms;
        float a0 = 0, a1 = 0, a2 = 0, a3 = 0;
        for (int e = rp[m]; e < rp[m + 1]; ++e) {
            uint2 u = *(const uint2*)(hperm + (long long)e * 64 + cg * 4);
            a0 += __builtin_bit_cast(float, u.x << 16);
            a1 += __builtin_bit_cast(float, u.x & 0xFFFF0000u);
            a2 += __builtin_bit_cast(float, u.y << 16);
            a3 += __builtin_bit_cast(float, u.y & 0xFFFF0000u);
        }
        unsigned* dst = (unsigned*)&As[m][cg * 4];
        dst[0] = f2b2(a0 > 0.f ? a0 : 0.f, a1 > 0.f ? a1 : 0.f);
        dst[1] = f2b2(a2 > 0.f ? a2 : 0.f, a3 > 0.f ? a3 : 0.f);
    }
    __syncthreads();

    const int lane = tid & 63, wave = tid >> 6;
    const int l16 = lane & 15, quad = lane >> 4;
    f32x4 acc[2][3] = {};
#pragma unroll
    for (int kk = 0; kk < 2; ++kk) {
#pragma unroll
        for (int mt2 = 0; mt2 < 2; ++mt2) {
            bf16x8 a = *(const bf16x8*)&As[(wave * 2 + mt2) * 16 + l16][kk * 32 + quad * 8];
#pragma unroll
            for (int nt = 0; nt < 3; ++nt) {
                bf16x8 b = *(const bf16x8*)&Bs[nt * 16 + l16][kk * 32 + quad * 8];
                acc[mt2][nt] = __builtin_amdgcn_mfma_f32_16x16x32_bf16(a, b, acc[mt2][nt], 0, 0, 0);
            }
        }
    }
#pragma unroll
    for (int mt2 = 0; mt2 < 2; ++mt2) {
#pragma unroll
        for (int nt = 0; nt < 3; ++nt) {
            int n = nt * 16 + l16;
            if (n < CC) {
                float bias = b2[n];
#pragma unroll
                for (int reg = 0; reg < 4; ++reg) {
                    long long m = m0 + (wave * 2 + mt2) * 16 + quad * 4 + reg;
                    if (m < NN) {
                        float* po = out + m * CC + n;
                        float v = acc[mt2][nt][reg];
                        if (chunk == 0) *po = v + bias;
                        else *po += v;
                    }
                }
            }
        }
    }
}

// ---------------- launch ----------------

extern "C" void kernel_launch(void* const* d_in, const int* in_sizes, int n_in,
                              void* d_out, int out_size, void* d_ws, size_t ws_size,
                              hipStream_t stream) {
    const float* x  = (const float*)d_in[0];
    const int*   ei = (const int*)d_in[1];
    const float* W1 = (const float*)d_in[2];
    const float* b1 = (const float*)d_in[3];
    const float* W2 = (const float*)d_in[4];
    const float* b2 = (const float*)d_in[5];
    float* out = (float*)d_out;

    char* ws = (char*)d_ws;
    size_t off = 0;
    auto alloc = [&](size_t bytes) { void* p = ws + off; off = (off + bytes + 255) & ~(size_t)255; return p; };
    int* fp     = (int*)alloc(4ll * NN);
    int* rank   = (int*)alloc(4ll * NN);
    int* mapped = (int*)alloc(4ll * NN);
    int* cnt    = (int*)alloc(4ll * NN);
    int* cur    = (int*)alloc(4ll * NN);
    int* rowptr = (int*)alloc(4ll * (NN + 2));
    int* col    = (int*)alloc(4ll * (NN + 64));
    int* bsums  = (int*)alloc(4ll * 2048);
    int* bofs   = (int*)alloc(4ll * 2048);
    unsigned short* W1T = (unsigned short*)alloc(2ll * HH * FF);
    unsigned short* W2T = (unsigned short*)alloc(2ll * 48 * HH);
    unsigned short* hperm = (unsigned short*)alloc(2ll * (NN + 64) * 64);

    hipLaunchKernelGGL(k_init,   dim3(NB256), dim3(256), 0, stream, fp, cnt, cur);
    hipLaunchKernelGGL(k_amin,   dim3(NB256), dim3(256), 0, stream, ei, fp);
    hipLaunchKernelGGL(k_count,  dim3(NB256), dim3(256), 0, stream, ei, fp, bsums);
    hipLaunchKernelGGL(k_scan,   dim3(1),     dim3(256), 0, stream, bsums, bofs, NB256);
    hipLaunchKernelGGL(k_rank,   dim3(NB256), dim3(256), 0, stream, ei, fp, bofs, rank);
    hipLaunchKernelGGL(k_mapped, dim3(NB256), dim3(256), 0, stream, ei, rank, mapped, cnt);
    hipLaunchKernelGGL(k_block_scan, dim3(NB256), dim3(256), 0, stream, cnt, rowptr, bsums, NN);
    hipLaunchKernelGGL(k_scan,   dim3(1),     dim3(256), 0, stream, bsums, bofs, NB256);
    hipLaunchKernelGGL(k_add_off,dim3(NB256), dim3(256), 0, stream, rowptr, bofs, NN);
    hipLaunchKernelGGL(k_scatter,dim3(NB256), dim3(256), 0, stream, mapped, rowptr, cur, col);
    hipLaunchKernelGGL(k_cvtW1,  dim3((HH * FF + 255) / 256), dim3(256), 0, stream, W1, W1T);
    hipLaunchKernelGGL(k_cvtW2,  dim3((48 * HH + 255) / 256), dim3(256), 0, stream, W2, W2T);

    const int NBH = (NN + 63) / 64;     // 7813
    const int NBO = (NN + 127) / 128;   // 3907
    for (int c = 0; c < 4; ++c) {
        hipLaunchKernelGGL(k_h,   dim3(NBH), dim3(256), 0, stream, x, W1T, b1, col, hperm, c);
        hipLaunchKernelGGL(k_out, dim3(NBO), dim3(256), 0, stream, hperm, W2T, b2, rowptr, out, c);
    }
}

// Round 4
// 876.486 us; speedup vs baseline: 2.9351x; 1.1056x over previous
//
#include <hip/hip_runtime.h>

#define NN 500000
#define FF 128
#define HH 256
#define CC 40
#define NB256 ((NN + 255) / 256)   // 1954

typedef __attribute__((ext_vector_type(8))) short bf16x8;
typedef __attribute__((ext_vector_type(4))) float f32x4;

__device__ inline unsigned short f2b(float f) {
    unsigned u = __builtin_bit_cast(unsigned, f);
    return (unsigned short)((u + 0x7FFF + ((u >> 16) & 1)) >> 16);
}
__device__ inline unsigned f2b2(float lo, float hi) {
    unsigned ul = __builtin_bit_cast(unsigned, lo);
    unsigned uh = __builtin_bit_cast(unsigned, hi);
    unsigned rl = (ul + 0x7FFF + ((ul >> 16) & 1)) >> 16;
    unsigned rh = (uh + 0x7FFF + ((uh >> 16) & 1)) >> 16;
    return rl | (rh << 16);
}

// ---------------- index / CSR kernels ----------------

__global__ void k_init(int* fp, int* cnt, int* cur) {
    int i = blockIdx.x * 256 + threadIdx.x;
    if (i < NN) { fp[i] = 0x7FFFFFFF; cnt[i] = 0; cur[i] = 0; }
}

__global__ void k_amin(const int* __restrict__ ei, int* fp) {
    int i = blockIdx.x * 256 + threadIdx.x;
    if (i < NN) atomicMin(&fp[ei[2 * i]], i);
}

__global__ void k_count(const int* __restrict__ ei, const int* __restrict__ fp,
                        int* __restrict__ bsums) {
    int i = blockIdx.x * 256 + threadIdx.x;
    int f = 0;
    if (i < NN) f = (fp[ei[2 * i]] == i) ? 1 : 0;
    __shared__ int sh[256];
    sh[threadIdx.x] = f;
    __syncthreads();
    for (int s = 128; s > 0; s >>= 1) {
        if (threadIdx.x < s) sh[threadIdx.x] += sh[threadIdx.x + s];
        __syncthreads();
    }
    if (threadIdx.x == 0) bsums[blockIdx.x] = sh[0];
}

__global__ void k_scan(const int* __restrict__ bsums, int* __restrict__ bofs, int nb) {
    __shared__ int sh[256];
    int carry = 0;
    for (int base = 0; base < nb; base += 256) {
        int i = base + threadIdx.x;
        int v = (i < nb) ? bsums[i] : 0;
        sh[threadIdx.x] = v;
        __syncthreads();
        for (int s = 1; s < 256; s <<= 1) {
            int t = (threadIdx.x >= s) ? sh[threadIdx.x - s] : 0;
            __syncthreads();
            sh[threadIdx.x] += t;
            __syncthreads();
        }
        if (i < nb) bofs[i] = carry + sh[threadIdx.x] - v;   // exclusive
        carry += sh[255];
        __syncthreads();
    }
}

__global__ void k_rank(const int* __restrict__ ei, const int* __restrict__ fp,
                       const int* __restrict__ bofs, int* __restrict__ rank) {
    int i = blockIdx.x * 256 + threadIdx.x;
    int s = 0, f = 0;
    if (i < NN) { s = ei[2 * i]; f = (fp[s] == i) ? 1 : 0; }
    __shared__ int sh[256];
    sh[threadIdx.x] = f;
    __syncthreads();
    for (int st = 1; st < 256; st <<= 1) {
        int t = (threadIdx.x >= st) ? sh[threadIdx.x - st] : 0;
        __syncthreads();
        sh[threadIdx.x] += t;
        __syncthreads();
    }
    if (f) rank[s] = bofs[blockIdx.x] + sh[threadIdx.x] - 1;
}

__global__ void k_mapped(const int* __restrict__ ei, const int* __restrict__ rank,
                         int* __restrict__ mapped, int* __restrict__ cnt) {
    int i = blockIdx.x * 256 + threadIdx.x;
    if (i < NN) {
        int s1 = ei[2 * i];
        int s2 = ei[2 * (long long)s1];
        int m = rank[s2];
        mapped[i] = m;
        atomicAdd(&cnt[m], 1);
    }
}

__global__ void k_block_scan(const int* __restrict__ in, int* __restrict__ outp,
                             int* __restrict__ bsums, int n) {
    int i = blockIdx.x * 256 + threadIdx.x;
    int v = (i < n) ? in[i] : 0;
    __shared__ int sh[256];
    sh[threadIdx.x] = v;
    __syncthreads();
    for (int s = 1; s < 256; s <<= 1) {
        int t = (threadIdx.x >= s) ? sh[threadIdx.x - s] : 0;
        __syncthreads();
        sh[threadIdx.x] += t;
        __syncthreads();
    }
    if (i < n) outp[i] = sh[threadIdx.x] - v;     // exclusive within block
    if (threadIdx.x == 255) bsums[blockIdx.x] = sh[255];
}

__global__ void k_add_off(int* __restrict__ outp, const int* __restrict__ bofs, int n) {
    int i = blockIdx.x * 256 + threadIdx.x;
    if (i < n) outp[i] += bofs[blockIdx.x];
    if (i == 0) outp[n] = n;                      // rowptr[NN] = NN (total edges)
}

__global__ void k_scatter(const int* __restrict__ mapped, const int* __restrict__ rowptr,
                          int* __restrict__ cur, int* __restrict__ col) {
    int i = blockIdx.x * 256 + threadIdx.x;
    if (i < NN) {
        int m = mapped[i];
        int loc = rowptr[m] + atomicAdd(&cur[m], 1);
        col[loc] = i;
    }
}

// W1T[n][k] n<HH k<FF ; W2T[n][k] n<48 (pad 0), k<HH
__global__ void k_cvt(const float* __restrict__ W1, const float* __restrict__ W2,
                      unsigned short* __restrict__ W1T, unsigned short* __restrict__ W2T) {
    int i = blockIdx.x * 256 + threadIdx.x;
    if (i < HH * FF) {
        int n = i >> 7, k = i & 127;
        W1T[i] = f2b(W1[k * HH + n]);
    }
    int j = i - HH * FF;
    if (j >= 0 && j < 48 * HH) {
        int n = j >> 8, k = j & 255;
        W2T[j] = (n < CC) ? f2b(W2[k * CC + n]) : (unsigned short)0;
    }
}

// ---------------- stage B1: hperm[j] = relu(x[col[j]] @ W1 + b1), full H=256, bf16 out ----------
// block: 64 permuted rows x 256 h-cols, K=128, 4 waves; B streamed from global (L1/L2-hot)

__global__ __launch_bounds__(256) void k_h(
    const float* __restrict__ x, const unsigned short* __restrict__ W1T,
    const float* __restrict__ b1, const int* __restrict__ col,
    unsigned short* __restrict__ hperm)
{
    __shared__ __align__(16) unsigned short Xs[64][136];   // A tile, then reused as H staging
    const int tid = threadIdx.x;
    const long long j0 = (long long)blockIdx.x * 64;

    // gather + convert x rows (4 threads/row, 8 float4 each)
    {
        int r = tid >> 2, q = tid & 3;
        long long j = j0 + r;
        int e = (j < NN) ? col[j] : 0;
        const float4* src = (const float4*)(x + (long long)e * FF + q * 32);
        unsigned* dst = (unsigned*)&Xs[r][q * 32];
#pragma unroll
        for (int it = 0; it < 8; ++it) {
            float4 v = src[it];
            dst[it * 2]     = f2b2(v.x, v.y);
            dst[it * 2 + 1] = f2b2(v.z, v.w);
        }
    }
    __syncthreads();

    const int lane = tid & 63, wave = tid >> 6;
    const int l16 = lane & 15, quad = lane >> 4;
    bf16x8 a[4];
#pragma unroll
    for (int kk = 0; kk < 4; ++kk)
        a[kk] = *(const bf16x8*)&Xs[wave * 16 + l16][kk * 32 + quad * 8];
    __syncthreads();   // all A fragments in regs; Xs now reusable for output staging

#pragma unroll
    for (int half = 0; half < 2; ++half) {
#pragma unroll
        for (int ntl = 0; ntl < 8; ++ntl) {
            int n16 = half * 128 + ntl * 16 + l16;   // this lane's output col
            f32x4 acc = {0, 0, 0, 0};
#pragma unroll
            for (int kk = 0; kk < 4; ++kk) {
                bf16x8 b = *(const bf16x8*)(W1T + (long long)n16 * FF + kk * 32 + quad * 8);
                acc = __builtin_amdgcn_mfma_f32_16x16x32_bf16(a[kk], b, acc, 0, 0, 0);
            }
            float bias = b1[n16];
#pragma unroll
            for (int reg = 0; reg < 4; ++reg) {       // C/D: row=quad*4+reg, col=l16
                float v = acc[reg] + bias;
                Xs[wave * 16 + quad * 4 + reg][ntl * 16 + l16] = f2b(v > 0.f ? v : 0.f);
            }
        }
        __syncthreads();
        {   // coalesced store of 64 rows x 128 cols (256 B per row)
            int r = tid >> 2, c = tid & 3;
            const uint4* srow = (const uint4*)&Xs[r][0];
            uint4* drow = (uint4*)(hperm + (j0 + r) * 256 + half * 128);
            drow[c]      = srow[c];
            drow[c + 4]  = srow[c + 4];
            drow[c + 8]  = srow[c + 8];
            drow[c + 12] = srow[c + 12];
        }
        __syncthreads();
    }
}

// ---------------- stage B2: out[m] = relu(segsum(hperm)) @ W2 + b2, K=256 ----------------
// block: 64 output segments, 256 threads; contiguous hperm runs; B streamed from global

__global__ __launch_bounds__(256) void k_out(
    const unsigned short* __restrict__ hperm, const unsigned short* __restrict__ W2T,
    const float* __restrict__ b2, const int* __restrict__ rowptr,
    float* __restrict__ out)
{
    __shared__ __align__(16) unsigned short As[64][264];  // [m][k] pad 8
    __shared__ int rp[65];
    const int tid = threadIdx.x;
    const long long m0 = (long long)blockIdx.x * 64;

    if (tid < 65) {
        long long mi = m0 + tid; if (mi > NN) mi = NN;
        rp[tid] = rowptr[mi];
    }
    __syncthreads();

    // segment-sum: thread = (ms, cg); 16 cols per thread; edges contiguous per segment
    const int cg = tid & 15, ms = tid >> 4;
#pragma unroll
    for (int p = 0; p < 4; ++p) {
        int m = p * 16 + ms;
        float s[16];
#pragma unroll
        for (int t = 0; t < 16; ++t) s[t] = 0.f;
        for (int e = rp[m]; e < rp[m + 1]; ++e) {
            const uint4* src = (const uint4*)(hperm + (long long)e * 256 + cg * 16);
            uint4 u0 = src[0], u1 = src[1];
            unsigned w[8] = {u0.x, u0.y, u0.z, u0.w, u1.x, u1.y, u1.z, u1.w};
#pragma unroll
            for (int t = 0; t < 8; ++t) {
                s[2 * t]     += __builtin_bit_cast(float, w[t] << 16);
                s[2 * t + 1] += __builtin_bit_cast(float, w[t] & 0xFFFF0000u);
            }
        }
        unsigned* dst = (unsigned*)&As[m][cg * 16];
#pragma unroll
        for (int t = 0; t < 8; ++t)
            dst[t] = f2b2(s[2 * t] > 0.f ? s[2 * t] : 0.f,
                          s[2 * t + 1] > 0.f ? s[2 * t + 1] : 0.f);
    }
    __syncthreads();

    const int lane = tid & 63, wave = tid >> 6;
    const int l16 = lane & 15, quad = lane >> 4;
    bf16x8 a[8];
#pragma unroll
    for (int kk = 0; kk < 8; ++kk)
        a[kk] = *(const bf16x8*)&As[wave * 16 + l16][kk * 32 + quad * 8];

    f32x4 acc[3] = {};
#pragma unroll
    for (int kk = 0; kk < 8; ++kk) {
#pragma unroll
        for (int nt = 0; nt < 3; ++nt) {
            bf16x8 b = *(const bf16x8*)(W2T + (nt * 16 + l16) * HH + kk * 32 + quad * 8);
            acc[nt] = __builtin_amdgcn_mfma_f32_16x16x32_bf16(a[kk], b, acc[nt], 0, 0, 0);
        }
    }
#pragma unroll
    for (int nt = 0; nt < 3; ++nt) {
        int n = nt * 16 + l16;
        if (n < CC) {
            float bias = b2[n];
#pragma unroll
            for (int reg = 0; reg < 4; ++reg) {
                long long m = m0 + wave * 16 + quad * 4 + reg;
                if (m < NN) out[m * CC + n] = acc[nt][reg] + bias;
            }
        }
    }
}

// ---------------- launch ----------------

extern "C" void kernel_launch(void* const* d_in, const int* in_sizes, int n_in,
                              void* d_out, int out_size, void* d_ws, size_t ws_size,
                              hipStream_t stream) {
    const float* x  = (const float*)d_in[0];
    const int*   ei = (const int*)d_in[1];
    const float* W1 = (const float*)d_in[2];
    const float* b1 = (const float*)d_in[3];
    const float* W2 = (const float*)d_in[4];
    const float* b2 = (const float*)d_in[5];
    float* out = (float*)d_out;

    char* ws = (char*)d_ws;
    size_t off = 0;
    auto alloc = [&](size_t bytes) { void* p = ws + off; off = (off + bytes + 255) & ~(size_t)255; return p; };
    int* fp     = (int*)alloc(4ll * NN);
    int* rank   = (int*)alloc(4ll * NN);
    int* mapped = (int*)alloc(4ll * NN);
    int* cnt    = (int*)alloc(4ll * NN);
    int* cur    = (int*)alloc(4ll * NN);
    int* rowptr = (int*)alloc(4ll * (NN + 2));
    int* col    = (int*)alloc(4ll * (NN + 64));
    int* bsums  = (int*)alloc(4ll * 2048);
    int* bofs   = (int*)alloc(4ll * 2048);
    unsigned short* W1T = (unsigned short*)alloc(2ll * HH * FF);
    unsigned short* W2T = (unsigned short*)alloc(2ll * 48 * HH);
    unsigned short* hperm = (unsigned short*)alloc(2ll * (NN + 64) * 256);  // 256 MB

    hipLaunchKernelGGL(k_init,   dim3(NB256), dim3(256), 0, stream, fp, cnt, cur);
    hipLaunchKernelGGL(k_amin,   dim3(NB256), dim3(256), 0, stream, ei, fp);
    hipLaunchKernelGGL(k_count,  dim3(NB256), dim3(256), 0, stream, ei, fp, bsums);
    hipLaunchKernelGGL(k_scan,   dim3(1),     dim3(256), 0, stream, bsums, bofs, NB256);
    hipLaunchKernelGGL(k_rank,   dim3(NB256), dim3(256), 0, stream, ei, fp, bofs, rank);
    hipLaunchKernelGGL(k_mapped, dim3(NB256), dim3(256), 0, stream, ei, rank, mapped, cnt);
    hipLaunchKernelGGL(k_block_scan, dim3(NB256), dim3(256), 0, stream, cnt, rowptr, bsums, NN);
    hipLaunchKernelGGL(k_scan,   dim3(1),     dim3(256), 0, stream, bsums, bofs, NB256);
    hipLaunchKernelGGL(k_add_off,dim3(NB256), dim3(256), 0, stream, rowptr, bofs, NN);
    hipLaunchKernelGGL(k_scatter,dim3(NB256), dim3(256), 0, stream, mapped, rowptr, cur, col);
    hipLaunchKernelGGL(k_cvt,    dim3((HH * FF + 48 * HH + 255) / 256), dim3(256), 0, stream,
                       W1, W2, W1T, W2T);

    const int NB64 = (NN + 63) / 64;    // 7813
    hipLaunchKernelGGL(k_h,   dim3(NB64), dim3(256), 0, stream, x, W1T, b1, col, hperm);
    hipLaunchKernelGGL(k_out, dim3(NB64), dim3(256), 0, stream, hperm, W2T, b2, rowptr, out);
}